// Round 4
// baseline (199.077 us; speedup 1.0000x reference)
//
#include <hip/hip_runtime.h>
#include <stdint.h>

// Problem shapes (fixed): B=32, N=900, C=91. ALL float32 in and out.
// d_in[0]: bboxes f32 [32,900,4] (cxcywh)   d_in[1]: logits f32 [32,900,91]
// d_out f32 concat: agg [32,900,4] | logits [32,900,91] | adj [32,900,900]
#define NQ 900
#define NB 32
#define WORDS 16            // u64 bitmask words per row (15 used, 1 pad)
#define ROWS_PER_BLK 30     // k_mask rows per block (30 blocks per batch)
#define MASK_BLKS (NB * (NQ / ROWS_PER_BLK))   // 960
#define LOG_F4 655200       // 2620800 floats / 4
#define COPY_BLKS ((LOG_F4 + 255) / 256)       // 2560
#define ADJ_ROWS_PER_BLK 12                    // 75 chunks per batch
#define ADJ_BLKS (NB * (NQ / ADJ_ROWS_PER_BLK))// 2400
#define NQ4 (NQ / 4)                           // 225 float4 per adj row

// element (f32) offsets inside d_out
#define AGG_ELE   0                    // 115200 elems
#define LOG_ELE   115200               // 2620800 elems
#define ADJ_ELE   2736000              // 25920000 elems

// workspace layout (preferred): bits [3.6864 MB] | labg [115.2 KB]
#define WS_BITS_BYTES  (sizeof(unsigned long long) * NB * NQ * WORDS)  // 3686400
#define WS_LABG_BYTES  (sizeof(int) * NB * NQ)                         // 115200
#define WS_NEEDED      (WS_BITS_BYTES + WS_LABG_BYTES)

// ---------------------------------------------------------------------------
// Kernel 1: blocks [0, COPY_BLKS): logits passthrough copy (pure-memory
// blocks dispatched FIRST so they saturate HBM while mask blocks compute).
// blocks [COPY_BLKS, COPY_BLKS+MASK_BLKS): pairwise GIoU > 0.9 bitmask,
// upper triangle (j >= i), exact reference f32 op order, contraction off.
// Two rows (r, r+15) processed per inner iteration to share the LDS
// j-operand loads between them.
// ---------------------------------------------------------------------------
__global__ __launch_bounds__(256) void k_mask(const float4* __restrict__ bb,
                                              unsigned long long* __restrict__ bits,
                                              const float4* __restrict__ logits,
                                              float4* __restrict__ logits_out)
{
#pragma clang fp contract(off)
    const int blk = blockIdx.x;
    if (blk < COPY_BLKS) {                  // copy role
        int i = blk * 256 + threadIdx.x;
        if (i < LOG_F4) logits_out[i] = logits[i];
        return;
    }
    const int mblk  = blk - COPY_BLKS;
    __shared__ float sx1[NQ], sy1[NQ], sx2[NQ], sy2[NQ], sar[NQ];
    const int b     = mblk / (NQ / ROWS_PER_BLK);
    const int chunk = mblk % (NQ / ROWS_PER_BLK);
    const int row0  = chunk * ROWS_PER_BLK;
    const int tid   = threadIdx.x;

    for (int i = tid; i < NQ; i += 256) {
        float4 q = bb[b * NQ + i];
        float cx = q.x, cy = q.y, w = q.z, h = q.w;
        float hw = 0.5f * w, hh = 0.5f * h;       // exact (pow2 scale)
        float x1 = cx - hw, y1 = cy - hh, x2 = cx + hw, y2 = cy + hh;
        sx1[i] = x1; sy1[i] = y1; sx2[i] = x2; sy2[i] = y2;
        sar[i] = (x2 - x1) * (y2 - y1);           // ref: area from xyxy
    }
    __syncthreads();

    const int wave = tid >> 6, lane = tid & 63;
    for (int rr = 0; rr < ROWS_PER_BLK / 2; ++rr) {
        const int ra = row0 + rr;                   // ra < rb
        const int rb = ra + ROWS_PER_BLK / 2;
        float ax1 = sx1[ra], ay1 = sy1[ra], ax2 = sx2[ra], ay2 = sy2[ra], aa = sar[ra];
        float bx1 = sx1[rb], by1 = sy1[rb], bx2 = sx2[rb], by2 = sy2[rb], ab = sar[rb];
        unsigned long long* rowa = bits + (size_t)(b * NQ + ra) * WORDS;
        unsigned long long* rowb = bits + (size_t)(b * NQ + rb) * WORDS;
        for (int t = 0; t < 4; ++t) {
            int word  = wave + 4 * t;      // 0..15
            int jbase = word << 6;
            bool do_a = (jbase + 64 > ra);           // word touches ra's upper tri
            bool do_b = (jbase + 64 > rb);
            int j = jbase + lane;
            float x1j = 0.f, y1j = 0.f, x2j = 0.f, y2j = 0.f, aj = 0.f;
            if (j < NQ) {
                x1j = sx1[j]; y1j = sy1[j]; x2j = sx2[j]; y2j = sy2[j]; aj = sar[j];
            }
            if (do_a) {
                bool pred = false;
                if (j >= ra && j < NQ) {
                    float ltx = fmaxf(ax1, x1j), lty = fmaxf(ay1, y1j);
                    float rbx = fminf(ax2, x2j), rby = fminf(ay2, y2j);
                    float iw  = fmaxf(rbx - ltx, 0.0f), ih = fmaxf(rby - lty, 0.0f);
                    float inter = iw * ih;
                    float uni   = aa + aj - inter;
                    float iou   = inter / uni;             // 0/0 -> NaN (degenerate)
                    float ex1 = fminf(ax1, x1j), ey1 = fminf(ay1, y1j);
                    float ex2 = fmaxf(ax2, x2j), ey2 = fmaxf(ay2, y2j);
                    float ew  = fmaxf(ex2 - ex1, 0.0f), eh2 = fmaxf(ey2 - ey1, 0.0f);
                    float ae  = ew * eh2;
                    float g   = iou - (ae - uni) / ae;
                    pred = (g > 0.9f);                     // NaN -> false, matches np
                }
                unsigned long long m = __ballot(pred);
                if (lane == 0) rowa[word] = m;
            } else {
                if (lane == 0) rowa[word] = 0ULL;
            }
            if (do_b) {
                bool pred = false;
                if (j >= rb && j < NQ) {
                    float ltx = fmaxf(bx1, x1j), lty = fmaxf(by1, y1j);
                    float rbx = fminf(bx2, x2j), rby = fminf(by2, y2j);
                    float iw  = fmaxf(rbx - ltx, 0.0f), ih = fmaxf(rby - lty, 0.0f);
                    float inter = iw * ih;
                    float uni   = ab + aj - inter;
                    float iou   = inter / uni;
                    float ex1 = fminf(bx1, x1j), ey1 = fminf(by1, y1j);
                    float ex2 = fmaxf(bx2, x2j), ey2 = fmaxf(by2, y2j);
                    float ew  = fmaxf(ex2 - ex1, 0.0f), eh2 = fmaxf(ey2 - ey1, 0.0f);
                    float ae  = ew * eh2;
                    float g   = iou - (ae - uni) / ae;
                    pred = (g > 0.9f);
                }
                unsigned long long m = __ballot(pred);
                if (lane == 0) rowb[word] = m;
            } else {
                if (lane == 0) rowb[word] = 0ULL;
            }
        }
    }
}

// ---------------------------------------------------------------------------
// Kernel 2: connected components (min-label propagation, one block/batch),
// then component-mean aggregation -> f32 agg. Whole 115.2 KB bit matrix
// staged to LDS once (coalesced 16B), convergence loop never touches global.
// ---------------------------------------------------------------------------
__global__ __launch_bounds__(1024) void k_label(const unsigned long long* __restrict__ bits,
                                                const float4* __restrict__ bb,
                                                int* __restrict__ labg,
                                                float4* __restrict__ agg_out)
{
    __shared__ unsigned long long sbits[NQ * WORDS];   // 115200 B
    __shared__ int   lab[NQ];
    __shared__ float scx[NQ], scy[NQ], sw[NQ], sh[NQ], scnt[NQ];
    __shared__ int   changed;
    const int b   = blockIdx.x;
    const int tid = threadIdx.x;
    const size_t base = (size_t)b * NQ;

    {
        const ulonglong2* src = (const ulonglong2*)(bits + base * WORDS);
        ulonglong2* dst = (ulonglong2*)sbits;
        for (int t = tid; t < NQ * WORDS / 2; t += 1024) dst[t] = src[t];
    }
    for (int i = tid; i < NQ; i += 1024) {
        scx[i] = 0.f; scy[i] = 0.f; sw[i] = 0.f; sh[i] = 0.f; scnt[i] = 0.f;
    }
    if (tid == 0) changed = 0;
    __syncthreads();

    for (int i = tid; i < NQ; i += 1024) {
        unsigned long long selfw = sbits[i * WORDS + (i >> 6)];
        bool alive = (selfw >> (i & 63)) & 1ULL;   // degenerate box: self-GIoU NaN
        lab[i] = alive ? i : -1;
    }
    __syncthreads();

    for (int iter = 0; iter < 1024; ++iter) {
        for (int i = tid; i < NQ; i += 1024) {
            int li = lab[i];
            if (li < 0) continue;
            const unsigned long long* rowp = sbits + i * WORDS;
            for (int k = i >> 6; k < 15; ++k) {
                unsigned long long w = rowp[k];
                while (w) {
                    int j = (k << 6) + __builtin_ctzll(w);
                    w &= w - 1;
                    int lj = lab[j];
                    if (lj < li)      { li = lj; changed = 1; }
                    else if (lj > li) { atomicMin(&lab[j], li); changed = 1; }
                }
            }
            if (li < lab[i]) atomicMin(&lab[i], li);
        }
        __syncthreads();
        for (int i = tid; i < NQ; i += 1024) {       // pointer-jump compress
            int li = lab[i];
            if (li > 0) {
                int l2 = lab[li];
                if (l2 < li) lab[i] = l2;            // benign race, monotone decrease
            }
        }
        __syncthreads();
        int done = (changed == 0);
        __syncthreads();
        if (done) break;
        if (tid == 0) changed = 0;
        __syncthreads();
    }

    for (int i = tid; i < NQ; i += 1024) {
        int li = lab[i];
        if (li >= 0) {
            float4 q = bb[base + i];
            atomicAdd(&scx[li], q.x);
            atomicAdd(&scy[li], q.y);
            atomicAdd(&sw [li], q.z);
            atomicAdd(&sh [li], q.w);
            atomicAdd(&scnt[li], 1.0f);
        }
    }
    __syncthreads();

    for (int i = tid; i < NQ; i += 1024) {
        int li = lab[i];
        labg[base + i] = li;
        float4 o;
        if (li >= 0) {
            float d = scnt[li] + 1e-6f;
            o.x = scx[li] / d; o.y = scy[li] / d;
            o.z = sw [li] / d; o.w = sh [li] / d;
        } else {
            o.x = 0.f; o.y = 0.f; o.z = 0.f; o.w = 0.f;   // ref: 0 / 1e-6 = 0
        }
        agg_out[base + i] = o;
    }
}

// ---------------------------------------------------------------------------
// Kernel 3: adj[b][i][j] = (lab[j]==lab[i] && alive) ? 1.0f : 0.0f
// 2400 blocks x 12 consecutive rows. Each thread loads its label int4 ONCE
// and reuses it across the 12 rows (12 coalesced 16B stores), amortizing
// block setup + label reads. Pure streaming write (104 MB).
// ---------------------------------------------------------------------------
__global__ __launch_bounds__(256) void k_adj(const int* __restrict__ labg,
                                             float4* __restrict__ adj)
{
    const int blk   = blockIdx.x;                 // 0..2399
    const int b     = blk / (NQ / ADJ_ROWS_PER_BLK);
    const int chunk = blk % (NQ / ADJ_ROWS_PER_BLK);
    const int row0  = chunk * ADJ_ROWS_PER_BLK;   // within batch
    __shared__ int sli[ADJ_ROWS_PER_BLK];
    if (threadIdx.x < ADJ_ROWS_PER_BLK)
        sli[threadIdx.x] = labg[b * NQ + row0 + threadIdx.x];
    __syncthreads();
    const int t = threadIdx.x;
    if (t >= NQ4) return;
    int4 l = ((const int4*)(labg + (size_t)b * NQ))[t];
    float4* out = adj + ((size_t)(b * NQ + row0)) * NQ4 + t;
    #pragma unroll
    for (int r = 0; r < ADJ_ROWS_PER_BLK; ++r) {
        int li = sli[r];
        float4 o;
        o.x = (l.x == li && li >= 0) ? 1.0f : 0.f;
        o.y = (l.y == li && li >= 0) ? 1.0f : 0.f;
        o.z = (l.z == li && li >= 0) ? 1.0f : 0.f;
        o.w = (l.w == li && li >= 0) ? 1.0f : 0.f;
        out[(size_t)r * NQ4] = o;
    }
}

// Fallback copy kernel (only used when d_ws is too small and scratch must
// alias the output buffer, forcing copy-last ordering).
__global__ __launch_bounds__(256) void k_copy(const float4* __restrict__ src,
                                              float4* __restrict__ dst)
{
    int i = blockIdx.x * 256 + threadIdx.x;
    if (i < LOG_F4) dst[i] = src[i];
}

// Fallback mask-only kernel (no fused copy; scratch aliases adj region).
__global__ __launch_bounds__(256) void k_mask_nf(const float4* __restrict__ bb,
                                                 unsigned long long* __restrict__ bits)
{
#pragma clang fp contract(off)
    __shared__ float sx1[NQ], sy1[NQ], sx2[NQ], sy2[NQ], sar[NQ];
    const int mblk  = blockIdx.x;
    const int b     = mblk / (NQ / ROWS_PER_BLK);
    const int chunk = mblk % (NQ / ROWS_PER_BLK);
    const int row0  = chunk * ROWS_PER_BLK;
    const int tid   = threadIdx.x;
    for (int i = tid; i < NQ; i += 256) {
        float4 q = bb[b * NQ + i];
        float cx = q.x, cy = q.y, w = q.z, h = q.w;
        float hw = 0.5f * w, hh = 0.5f * h;
        float x1 = cx - hw, y1 = cy - hh, x2 = cx + hw, y2 = cy + hh;
        sx1[i] = x1; sy1[i] = y1; sx2[i] = x2; sy2[i] = y2;
        sar[i] = (x2 - x1) * (y2 - y1);
    }
    __syncthreads();
    const int wave = tid >> 6, lane = tid & 63;
    for (int r = row0; r < row0 + ROWS_PER_BLK; ++r) {
        float x1i = sx1[r], y1i = sy1[r], x2i = sx2[r], y2i = sy2[r], ai = sar[r];
        unsigned long long* rowp = bits + (size_t)(b * NQ + r) * WORDS;
        for (int t = 0; t < 4; ++t) {
            int word  = wave + 4 * t;
            int jbase = word << 6;
            if (jbase + 64 <= r) { if (lane == 0) rowp[word] = 0ULL; continue; }
            int j = jbase + lane;
            bool pred = false;
            if (j >= r && j < NQ) {
                float x1j = sx1[j], y1j = sy1[j], x2j = sx2[j], y2j = sy2[j], aj = sar[j];
                float ltx = fmaxf(x1i, x1j), lty = fmaxf(y1i, y1j);
                float rbx = fminf(x2i, x2j), rby = fminf(y2i, y2j);
                float iw  = fmaxf(rbx - ltx, 0.0f), ih = fmaxf(rby - lty, 0.0f);
                float inter = iw * ih;
                float uni   = ai + aj - inter;
                float iou   = inter / uni;
                float ex1 = fminf(x1i, x1j), ey1 = fminf(y1i, y1j);
                float ex2 = fmaxf(x2i, x2j), ey2 = fmaxf(y2i, y2j);
                float ew  = fmaxf(ex2 - ex1, 0.0f), eh2 = fmaxf(ey2 - ey1, 0.0f);
                float ae  = ew * eh2;
                float g   = iou - (ae - uni) / ae;
                pred = (g > 0.9f);
            }
            unsigned long long m = __ballot(pred);
            if (lane == 0) rowp[word] = m;
        }
    }
}

extern "C" void kernel_launch(void* const* d_in, const int* in_sizes, int n_in,
                              void* d_out, int out_size, void* d_ws, size_t ws_size,
                              hipStream_t stream) {
    (void)in_sizes; (void)n_in; (void)out_size;
    const float4* bb = (const float4*)d_in[0];
    const float4* logits = (const float4*)d_in[1];
    float* outf = (float*)d_out;

    float4* agg     = (float4*)(outf + AGG_ELE);
    float4* adj     = (float4*)(outf + ADJ_ELE);
    float4* log_out = (float4*)(outf + LOG_ELE);

    if (d_ws != nullptr && ws_size >= WS_NEEDED) {
        // preferred: scratch in workspace, 3 dispatches, copy fused first.
        unsigned long long* bits = (unsigned long long*)d_ws;
        int* labg = (int*)((char*)d_ws + WS_BITS_BYTES);
        hipLaunchKernelGGL(k_mask,  dim3(MASK_BLKS + COPY_BLKS), dim3(256), 0, stream,
                           bb, bits, logits, log_out);
        hipLaunchKernelGGL(k_label, dim3(NB), dim3(1024), 0, stream, bits, bb, labg, agg);
        hipLaunchKernelGGL(k_adj,   dim3(ADJ_BLKS), dim3(256), 0, stream, labg, adj);
    } else {
        // fallback: scratch aliases output (bits -> adj start, labels ->
        // logits start), copy must come last.
        unsigned long long* bits = (unsigned long long*)(outf + ADJ_ELE);
        int* labg = (int*)(outf + LOG_ELE);
        hipLaunchKernelGGL(k_mask_nf, dim3(MASK_BLKS), dim3(256), 0, stream, bb, bits);
        hipLaunchKernelGGL(k_label,   dim3(NB), dim3(1024), 0, stream, bits, bb, labg, agg);
        hipLaunchKernelGGL(k_adj,     dim3(ADJ_BLKS), dim3(256), 0, stream, labg, adj);
        hipLaunchKernelGGL(k_copy,    dim3(COPY_BLKS), dim3(256), 0, stream, logits, log_out);
    }
}

// Round 5
// 168.767 us; speedup vs baseline: 1.1796x; 1.1796x over previous
//
#include <hip/hip_runtime.h>
#include <stdint.h>

// Problem shapes (fixed): B=32, N=900, C=91. ALL float32 in and out.
// d_in[0]: bboxes f32 [32,900,4] (cxcywh)   d_in[1]: logits f32 [32,900,91]
// d_out f32 concat: agg [32,900,4] | logits [32,900,91] | adj [32,900,900]
#define NQ 900
#define NB 32
#define WORDS 16            // u64 bitmask words per row (15 used, 1 pad)
#define ROWS_PER_BLK 15     // k_mask rows per block (60 blocks per batch)
#define MASK_BLKS (NB * (NQ / ROWS_PER_BLK))   // 1920
#define LOG_F4 655200       // 2620800 floats / 4
#define COPY_BLKS ((LOG_F4 + 255) / 256)       // 2560
#define ADJ_ROWS_PER_BLK 12                    // 75 chunks per batch
#define ADJ_BLKS (NB * (NQ / ADJ_ROWS_PER_BLK))// 2400
#define NQ4 (NQ / 4)                           // 225 float4 per adj row

// element (f32) offsets inside d_out
#define AGG_ELE   0                    // 115200 elems
#define LOG_ELE   115200               // 2620800 elems
#define ADJ_ELE   2736000              // 25920000 elems

// workspace layout (preferred): bits [3.6864 MB] | labg [115.2 KB]
#define WS_BITS_BYTES  (sizeof(unsigned long long) * NB * NQ * WORDS)  // 3686400
#define WS_LABG_BYTES  (sizeof(int) * NB * NQ)                         // 115200
#define WS_NEEDED      (WS_BITS_BYTES + WS_LABG_BYTES)

// ---------------------------------------------------------------------------
// GIoU > 0.9 predicate for one 64-pair word, with conservative prune.
// Cheap phase (no divides): inter > 0.88*uni is NECESSARY for GIoU > 0.9
//   (penalty >= 0 up to ~1ulp; 2% margin >> rounding slack; NaN/degenerate
//   compare false -> pruned, same as reference NaN -> false).
// Exact phase (rare, ~1 word/row): byte-identical reference f32 op order.
// ---------------------------------------------------------------------------
__device__ __forceinline__ unsigned long long giou_word(
    int r, int j, int nq_ok,
    float x1i, float y1i, float x2i, float y2i, float ai,
    const float* __restrict__ sx1, const float* __restrict__ sy1,
    const float* __restrict__ sx2, const float* __restrict__ sy2,
    const float* __restrict__ sar)
{
    bool  cand = false;
    float x1j = 0.f, y1j = 0.f, x2j = 0.f, y2j = 0.f, aj = 0.f;
    float inter = 0.f, uni = 0.f;
    if (nq_ok) {
        x1j = sx1[j]; y1j = sy1[j]; x2j = sx2[j]; y2j = sy2[j]; aj = sar[j];
        float ltx = fmaxf(x1i, x1j), lty = fmaxf(y1i, y1j);
        float rbx = fminf(x2i, x2j), rby = fminf(y2i, y2j);
        float iw  = fmaxf(rbx - ltx, 0.0f), ih = fmaxf(rby - lty, 0.0f);
        inter = iw * ih;
        uni   = ai + aj - inter;
        cand  = (j >= r) && (inter > 0.88f * uni);
    }
    unsigned long long cm = __ballot(cand);
    unsigned long long m  = 0ULL;
    if (cm) {                          // wave-uniform branch
        bool pred = false;
        if (cand) {
            float iou = inter / uni;                       // 0/0 never here
            float ex1 = fminf(x1i, x1j), ey1 = fminf(y1i, y1j);
            float ex2 = fmaxf(x2i, x2j), ey2 = fmaxf(y2i, y2j);
            float ew  = fmaxf(ex2 - ex1, 0.0f), eh2 = fmaxf(ey2 - ey1, 0.0f);
            float ae  = ew * eh2;
            float g   = iou - (ae - uni) / ae;
            pred = (g > 0.9f);                             // NaN -> false
        }
        m = __ballot(pred);
    }
    return m;
}

// ---------------------------------------------------------------------------
// Kernel 1: blocks [0, MASK_BLKS): pairwise GIoU bitmask, upper triangle.
// blocks [MASK_BLKS, +COPY_BLKS): logits passthrough copy (independent work
// folded into the same launch; mask blocks first since they're the long pole).
// ---------------------------------------------------------------------------
__global__ __launch_bounds__(256) void k_mask(const float4* __restrict__ bb,
                                              unsigned long long* __restrict__ bits,
                                              const float4* __restrict__ logits,
                                              float4* __restrict__ logits_out)
{
#pragma clang fp contract(off)
    const int blk = blockIdx.x;
    if (blk >= MASK_BLKS) {                 // copy role
        int i = (blk - MASK_BLKS) * 256 + threadIdx.x;
        if (i < LOG_F4) logits_out[i] = logits[i];
        return;
    }
    __shared__ float sx1[NQ], sy1[NQ], sx2[NQ], sy2[NQ], sar[NQ];
    const int b     = blk / (NQ / ROWS_PER_BLK);
    const int chunk = blk % (NQ / ROWS_PER_BLK);
    const int row0  = chunk * ROWS_PER_BLK;
    const int tid   = threadIdx.x;

    for (int i = tid; i < NQ; i += 256) {
        float4 q = bb[b * NQ + i];
        float cx = q.x, cy = q.y, w = q.z, h = q.w;
        float hw = 0.5f * w, hh = 0.5f * h;       // exact (pow2 scale)
        float x1 = cx - hw, y1 = cy - hh, x2 = cx + hw, y2 = cy + hh;
        sx1[i] = x1; sy1[i] = y1; sx2[i] = x2; sy2[i] = y2;
        sar[i] = (x2 - x1) * (y2 - y1);           // ref: area from xyxy
    }
    __syncthreads();

    const int wave = tid >> 6, lane = tid & 63;
    for (int r = row0; r < row0 + ROWS_PER_BLK; ++r) {
        float x1i = sx1[r], y1i = sy1[r], x2i = sx2[r], y2i = sy2[r], ai = sar[r];
        unsigned long long* rowp = bits + (size_t)(b * NQ + r) * WORDS;
        for (int t = 0; t < 4; ++t) {
            int word  = wave + 4 * t;      // 0..15
            int jbase = word << 6;
            if (jbase + 64 <= r) {         // whole word strictly below diagonal
                if (lane == 0) rowp[word] = 0ULL;
                continue;
            }
            int j = jbase + lane;
            unsigned long long m = giou_word(r, j, j < NQ,
                                             x1i, y1i, x2i, y2i, ai,
                                             sx1, sy1, sx2, sy2, sar);
            if (lane == 0) rowp[word] = m;
        }
    }
}

// ---------------------------------------------------------------------------
// Kernel 2: connected components (min-label propagation, one block/batch),
// then component-mean aggregation -> f32 agg. Whole 115.2 KB bit matrix
// staged to LDS once (coalesced 16B), convergence loop never touches global.
// ---------------------------------------------------------------------------
__global__ __launch_bounds__(1024) void k_label(const unsigned long long* __restrict__ bits,
                                                const float4* __restrict__ bb,
                                                int* __restrict__ labg,
                                                float4* __restrict__ agg_out)
{
    __shared__ unsigned long long sbits[NQ * WORDS];   // 115200 B
    __shared__ int   lab[NQ];
    __shared__ float scx[NQ], scy[NQ], sw[NQ], sh[NQ], scnt[NQ];
    __shared__ int   changed;
    const int b   = blockIdx.x;
    const int tid = threadIdx.x;
    const size_t base = (size_t)b * NQ;

    {
        const ulonglong2* src = (const ulonglong2*)(bits + base * WORDS);
        ulonglong2* dst = (ulonglong2*)sbits;
        for (int t = tid; t < NQ * WORDS / 2; t += 1024) dst[t] = src[t];
    }
    for (int i = tid; i < NQ; i += 1024) {
        scx[i] = 0.f; scy[i] = 0.f; sw[i] = 0.f; sh[i] = 0.f; scnt[i] = 0.f;
    }
    if (tid == 0) changed = 0;
    __syncthreads();

    for (int i = tid; i < NQ; i += 1024) {
        unsigned long long selfw = sbits[i * WORDS + (i >> 6)];
        bool alive = (selfw >> (i & 63)) & 1ULL;   // degenerate box: self-GIoU NaN
        lab[i] = alive ? i : -1;
    }
    __syncthreads();

    for (int iter = 0; iter < 1024; ++iter) {
        for (int i = tid; i < NQ; i += 1024) {
            int li = lab[i];
            if (li < 0) continue;
            const unsigned long long* rowp = sbits + i * WORDS;
            for (int k = i >> 6; k < 15; ++k) {
                unsigned long long w = rowp[k];
                while (w) {
                    int j = (k << 6) + __builtin_ctzll(w);
                    w &= w - 1;
                    int lj = lab[j];
                    if (lj < li)      { li = lj; changed = 1; }
                    else if (lj > li) { atomicMin(&lab[j], li); changed = 1; }
                }
            }
            if (li < lab[i]) atomicMin(&lab[i], li);
        }
        __syncthreads();
        for (int i = tid; i < NQ; i += 1024) {       // pointer-jump compress
            int li = lab[i];
            if (li > 0) {
                int l2 = lab[li];
                if (l2 < li) lab[i] = l2;            // benign race, monotone decrease
            }
        }
        __syncthreads();
        int done = (changed == 0);
        __syncthreads();
        if (done) break;
        if (tid == 0) changed = 0;
        __syncthreads();
    }

    for (int i = tid; i < NQ; i += 1024) {
        int li = lab[i];
        if (li >= 0) {
            float4 q = bb[base + i];
            atomicAdd(&scx[li], q.x);
            atomicAdd(&scy[li], q.y);
            atomicAdd(&sw [li], q.z);
            atomicAdd(&sh [li], q.w);
            atomicAdd(&scnt[li], 1.0f);
        }
    }
    __syncthreads();

    for (int i = tid; i < NQ; i += 1024) {
        int li = lab[i];
        labg[base + i] = li;
        float4 o;
        if (li >= 0) {
            float d = scnt[li] + 1e-6f;
            o.x = scx[li] / d; o.y = scy[li] / d;
            o.z = sw [li] / d; o.w = sh [li] / d;
        } else {
            o.x = 0.f; o.y = 0.f; o.z = 0.f; o.w = 0.f;   // ref: 0 / 1e-6 = 0
        }
        agg_out[base + i] = o;
    }
}

// ---------------------------------------------------------------------------
// Kernel 3: adj[b][i][j] = (lab[j]==lab[i] && alive) ? 1.0f : 0.0f
// 2400 blocks x 12 consecutive rows; each thread loads its label int4 once
// and issues 12 coalesced 16B stores. Pure streaming write (104 MB).
// ---------------------------------------------------------------------------
__global__ __launch_bounds__(256) void k_adj(const int* __restrict__ labg,
                                             float4* __restrict__ adj)
{
    const int blk   = blockIdx.x;                 // 0..2399
    const int b     = blk / (NQ / ADJ_ROWS_PER_BLK);
    const int chunk = blk % (NQ / ADJ_ROWS_PER_BLK);
    const int row0  = chunk * ADJ_ROWS_PER_BLK;   // within batch
    __shared__ int sli[ADJ_ROWS_PER_BLK];
    if (threadIdx.x < ADJ_ROWS_PER_BLK)
        sli[threadIdx.x] = labg[b * NQ + row0 + threadIdx.x];
    __syncthreads();
    const int t = threadIdx.x;
    if (t >= NQ4) return;
    int4 l = ((const int4*)(labg + (size_t)b * NQ))[t];
    float4* out = adj + ((size_t)(b * NQ + row0)) * NQ4 + t;
    #pragma unroll
    for (int r = 0; r < ADJ_ROWS_PER_BLK; ++r) {
        int li = sli[r];
        float4 o;
        o.x = (l.x == li && li >= 0) ? 1.0f : 0.f;
        o.y = (l.y == li && li >= 0) ? 1.0f : 0.f;
        o.z = (l.z == li && li >= 0) ? 1.0f : 0.f;
        o.w = (l.w == li && li >= 0) ? 1.0f : 0.f;
        out[(size_t)r * NQ4] = o;
    }
}

// Fallback copy kernel (only used when d_ws is too small and scratch must
// alias the output buffer, forcing copy-last ordering).
__global__ __launch_bounds__(256) void k_copy(const float4* __restrict__ src,
                                              float4* __restrict__ dst)
{
    int i = blockIdx.x * 256 + threadIdx.x;
    if (i < LOG_F4) dst[i] = src[i];
}

// Fallback mask-only kernel (no fused copy; scratch aliases adj region).
__global__ __launch_bounds__(256) void k_mask_nf(const float4* __restrict__ bb,
                                                 unsigned long long* __restrict__ bits)
{
#pragma clang fp contract(off)
    __shared__ float sx1[NQ], sy1[NQ], sx2[NQ], sy2[NQ], sar[NQ];
    const int mblk  = blockIdx.x;
    const int b     = mblk / (NQ / ROWS_PER_BLK);
    const int chunk = mblk % (NQ / ROWS_PER_BLK);
    const int row0  = chunk * ROWS_PER_BLK;
    const int tid   = threadIdx.x;
    for (int i = tid; i < NQ; i += 256) {
        float4 q = bb[b * NQ + i];
        float cx = q.x, cy = q.y, w = q.z, h = q.w;
        float hw = 0.5f * w, hh = 0.5f * h;
        float x1 = cx - hw, y1 = cy - hh, x2 = cx + hw, y2 = cy + hh;
        sx1[i] = x1; sy1[i] = y1; sx2[i] = x2; sy2[i] = y2;
        sar[i] = (x2 - x1) * (y2 - y1);
    }
    __syncthreads();
    const int wave = tid >> 6, lane = tid & 63;
    for (int r = row0; r < row0 + ROWS_PER_BLK; ++r) {
        float x1i = sx1[r], y1i = sy1[r], x2i = sx2[r], y2i = sy2[r], ai = sar[r];
        unsigned long long* rowp = bits + (size_t)(b * NQ + r) * WORDS;
        for (int t = 0; t < 4; ++t) {
            int word  = wave + 4 * t;
            int jbase = word << 6;
            if (jbase + 64 <= r) { if (lane == 0) rowp[word] = 0ULL; continue; }
            int j = jbase + lane;
            unsigned long long m = giou_word(r, j, j < NQ,
                                             x1i, y1i, x2i, y2i, ai,
                                             sx1, sy1, sx2, sy2, sar);
            if (lane == 0) rowp[word] = m;
        }
    }
}

extern "C" void kernel_launch(void* const* d_in, const int* in_sizes, int n_in,
                              void* d_out, int out_size, void* d_ws, size_t ws_size,
                              hipStream_t stream) {
    (void)in_sizes; (void)n_in; (void)out_size;
    const float4* bb = (const float4*)d_in[0];
    const float4* logits = (const float4*)d_in[1];
    float* outf = (float*)d_out;

    float4* agg     = (float4*)(outf + AGG_ELE);
    float4* adj     = (float4*)(outf + ADJ_ELE);
    float4* log_out = (float4*)(outf + LOG_ELE);

    if (d_ws != nullptr && ws_size >= WS_NEEDED) {
        // preferred: scratch in workspace, 3 dispatches, copy fused (last).
        unsigned long long* bits = (unsigned long long*)d_ws;
        int* labg = (int*)((char*)d_ws + WS_BITS_BYTES);
        hipLaunchKernelGGL(k_mask,  dim3(MASK_BLKS + COPY_BLKS), dim3(256), 0, stream,
                           bb, bits, logits, log_out);
        hipLaunchKernelGGL(k_label, dim3(NB), dim3(1024), 0, stream, bits, bb, labg, agg);
        hipLaunchKernelGGL(k_adj,   dim3(ADJ_BLKS), dim3(256), 0, stream, labg, adj);
    } else {
        // fallback: scratch aliases output (bits -> adj start, labels ->
        // logits start), copy must come last.
        unsigned long long* bits = (unsigned long long*)(outf + ADJ_ELE);
        int* labg = (int*)(outf + LOG_ELE);
        hipLaunchKernelGGL(k_mask_nf, dim3(MASK_BLKS), dim3(256), 0, stream, bb, bits);
        hipLaunchKernelGGL(k_label,   dim3(NB), dim3(1024), 0, stream, bits, bb, labg, agg);
        hipLaunchKernelGGL(k_adj,     dim3(ADJ_BLKS), dim3(256), 0, stream, labg, adj);
        hipLaunchKernelGGL(k_copy,    dim3(COPY_BLKS), dim3(256), 0, stream, logits, log_out);
    }
}